// Round 5
// baseline (285.838 us; speedup 1.0000x reference)
//
#include <hip/hip_runtime.h>
#include <hip/hip_cooperative_groups.h>

namespace cg = cooperative_groups;

#define D_IN  128
#define D_OUT 32
#define H     512
#define W     512
#define W4    128          // W/4 float4 lanes per row
#define HB    64           // output H rows per block
#define ZR    (HB + 8)     // z rows incl. h-halo (72)
#define NTHR  512
#define NHT   (H / HB)     // 8 h-tiles
#define CONV_GRID (D_OUT * NHT)   // 256 blocks = 1 per CU (LDS-forced)

// v6: ONE cooperative kernel = conv + grid min/max + normalize.
// v1-v5 showed total ~= conv + 157us fixed tail (norm kernel + launch gaps);
// here the output tile lives in registers across grid.sync() so the 33.5 MB
// bufA round-trip and the second launch vanish.
// HB=64 -> 144 KiB dynamic LDS -> exactly 1 block/CU, grid 256 = CU count
// (co-residency guaranteed). __launch_bounds__(512,2) -> VGPR cap 256
// (v5 lesson: default cap 128 spilled the register-resident working set).
extern __shared__ float zbuf[];   // ZR*W floats = 147456 B

__global__ __launch_bounds__(NTHR, 2)
void conv3d_all(const float* __restrict__ inp, float* __restrict__ out,
                const float* __restrict__ bxy_p, const float* __restrict__ bz_p,
                float* __restrict__ blkMin, float* __restrict__ blkMax) {
    __shared__ float smin[8], smax[8];

    const int tid = threadIdx.x;
    const int d  = blockIdx.x >> 3;        // 0..31
    const int h0 = (blockIdx.x & 7) * HB;  // 8 h-tiles

    const float bz = bz_p[0], bx = bxy_p[0];
    const float iz = 1.0f / (2.0f * bz * bz);
    const float ix = 1.0f / (2.0f * bx * bx);
    float wz[9], wx[9];
#pragma unroll
    for (int k = 0; k < 9; ++k) {
        float dd = (float)(k - 4);
        wz[k] = expf(-dd * dd * iz);
        wx[k] = expf(-dd * dd * ix);
    }

    const float4* in4 = (const float4*)inp;
    float4* z4 = (float4*)zbuf;

    const int dinBase = 4 * d - 3;
    const bool interior = (d >= 1) && (d <= 30);   // all 9 z-taps in range

    // ---- Step 1: z-conv (stride 4, pad 3) into zbuf rows [h0-4, h0+68) ----
    for (int t = tid; t < ZR * W4; t += NTHR) {    // 18 iterations
        int r  = t >> 7;            // 0..71 (wave-uniform)
        int c4 = t & (W4 - 1);
        int h  = h0 - 4 + r;
        float4 acc = make_float4(0.f, 0.f, 0.f, 0.f);
        if ((unsigned)h < H) {
            const float4* p = in4 + (ptrdiff_t)dinBase * (H * W4) + h * W4 + c4;
            if (interior) {
                float4 vv[9];
#pragma unroll
                for (int k = 0; k < 9; ++k) vv[k] = p[k * (H * W4)];
                __builtin_amdgcn_sched_barrier(0);   // keep all 9 loads in flight
#pragma unroll
                for (int k = 0; k < 9; ++k) {
                    acc.x += vv[k].x * wz[k]; acc.y += vv[k].y * wz[k];
                    acc.z += vv[k].z * wz[k]; acc.w += vv[k].w * wz[k];
                }
            } else {
#pragma unroll
                for (int k = 0; k < 9; ++k) {
                    int din = dinBase + k;   // wave-uniform predicate
                    if ((unsigned)din < D_IN) {
                        float4 v = p[k * (H * W4)];
                        acc.x += v.x * wz[k]; acc.y += v.y * wz[k];
                        acc.z += v.z * wz[k]; acc.w += v.w * wz[k];
                    }
                }
            }
        }
        z4[t] = acc;
    }
    __syncthreads();

    // ---- Step 2: fused h-conv + w-conv into REGISTERS (16 float4/thread) ----
    const int lane = tid & 63;
    float lmin =  3.402823466e38f;
    float lmax = -3.402823466e38f;
    float4 oreg[16];

#pragma unroll
    for (int j = 0; j < 16; ++j) {             // HB*W4/NTHR = 16
        int pos = j * NTHR + tid;
        int r   = pos >> 7;                    // 0..63 (wave-uniform)
        int c4  = pos & (W4 - 1);              // consecutive across lanes

        // h-conv at (r, c4)
        float4 v = make_float4(0.f, 0.f, 0.f, 0.f);
#pragma unroll
        for (int k = 0; k < 9; ++k) {
            float4 z = z4[(r + k) * W4 + c4];
            v.x += z.x * wx[k]; v.y += z.y * wx[k];
            v.z += z.z * wx[k]; v.w += z.w * wx[k];
        }

        // w-neighbors from adjacent lanes
        float4 va, vc;
        va.x = __shfl_up(v.x, 1, 64);   va.y = __shfl_up(v.y, 1, 64);
        va.z = __shfl_up(v.z, 1, 64);   va.w = __shfl_up(v.w, 1, 64);
        vc.x = __shfl_down(v.x, 1, 64); vc.y = __shfl_down(v.y, 1, 64);
        vc.z = __shfl_down(v.z, 1, 64); vc.w = __shfl_down(v.w, 1, 64);

        // wave-edge lanes recompute neighbor column (OOB -> zero = w pad)
        if (lane == 0 || lane == 63) {
            int c4n = c4 + ((lane == 0) ? -1 : 1);
            float4 vn = make_float4(0.f, 0.f, 0.f, 0.f);
            if ((unsigned)c4n < W4) {
#pragma unroll
                for (int k = 0; k < 9; ++k) {
                    float4 z = z4[(r + k) * W4 + c4n];
                    vn.x += z.x * wx[k]; vn.y += z.y * wx[k];
                    vn.z += z.z * wx[k]; vn.w += z.w * wx[k];
                }
            }
            if (lane == 0) va = vn; else vc = vn;
        }

        float win[12] = {va.x, va.y, va.z, va.w,
                         v.x,  v.y,  v.z,  v.w,
                         vc.x, vc.y, vc.z, vc.w};
        float4 o = make_float4(0.f, 0.f, 0.f, 0.f);
#pragma unroll
        for (int k = 0; k < 9; ++k) {
            o.x += win[k]     * wx[k];
            o.y += win[k + 1] * wx[k];
            o.z += win[k + 2] * wx[k];
            o.w += win[k + 3] * wx[k];
        }
        oreg[j] = o;
        lmin = fminf(lmin, fminf(fminf(o.x, o.y), fminf(o.z, o.w)));
        lmax = fmaxf(lmax, fmaxf(fmaxf(o.x, o.y), fmaxf(o.z, o.w)));
    }

    // ---- block min/max -> blkMin/blkMax[blockIdx.x] ----
#pragma unroll
    for (int off = 32; off > 0; off >>= 1) {
        lmin = fminf(lmin, __shfl_down(lmin, off, 64));
        lmax = fmaxf(lmax, __shfl_down(lmax, off, 64));
    }
    int wv = tid >> 6;  // 0..7
    if (lane == 0) { smin[wv] = lmin; smax[wv] = lmax; }
    __syncthreads();
    if (tid == 0) {
        float mn = smin[0], mx = smax[0];
#pragma unroll
        for (int i = 1; i < 8; ++i) { mn = fminf(mn, smin[i]); mx = fmaxf(mx, smax[i]); }
        blkMin[blockIdx.x] = mn;
        blkMax[blockIdx.x] = mx;
    }

    // ---- grid-wide barrier; then every block reduces the 256 entries ----
    cg::this_grid().sync();

    float gmn = blkMin[tid & (CONV_GRID - 1)];
    float gmx = blkMax[tid & (CONV_GRID - 1)];
#pragma unroll
    for (int off = 32; off > 0; off >>= 1) {
        gmn = fminf(gmn, __shfl_down(gmn, off, 64));
        gmx = fmaxf(gmx, __shfl_down(gmx, off, 64));
    }
    if (lane == 0) { smin[wv] = gmn; smax[wv] = gmx; }
    __syncthreads();
    float mn = smin[0], mx = smax[0];
#pragma unroll
    for (int i = 1; i < 8; ++i) { mn = fminf(mn, smin[i]); mx = fmaxf(mx, smax[i]); }
    const float inv = 1.0f / (mx - mn);

    // ---- normalize registers, single write of the final output ----
    float4* out4 = (float4*)out;
#pragma unroll
    for (int j = 0; j < 16; ++j) {
        int pos = j * NTHR + tid;
        int r   = pos >> 7;
        int c4  = pos & (W4 - 1);
        float4 o = oreg[j];
        out4[(d * H + h0 + r) * W4 + c4] =
            make_float4((o.x - mn) * inv, (o.y - mn) * inv,
                        (o.z - mn) * inv, (o.w - mn) * inv);
    }
}

extern "C" void kernel_launch(void* const* d_in, const int* in_sizes, int n_in,
                              void* d_out, int out_size, void* d_ws, size_t ws_size,
                              hipStream_t stream) {
    const float* inp    = (const float*)d_in[0];
    // mu_z / sig_z only produce a positive global scale, which cancels in the
    // min-max normalization -> unused.
    const float* bet_xy = (const float*)d_in[3];
    const float* bet_z  = (const float*)d_in[4];
    float* out = (float*)d_out;

    char* ws = (char*)d_ws;
    float* blkMin = (float*)(ws + 4096);   // 256 floats
    float* blkMax = (float*)(ws + 8192);   // 256 floats

    void* args[] = { (void*)&inp, (void*)&out, (void*)&bet_xy, (void*)&bet_z,
                     (void*)&blkMin, (void*)&blkMax };
    hipLaunchCooperativeKernel((const void*)conv3d_all,
                               dim3(CONV_GRID), dim3(NTHR),
                               args, ZR * W * sizeof(float), stream);
}

// Round 6
// 248.465 us; speedup vs baseline: 1.1504x; 1.1504x over previous
//
#include <hip/hip_runtime.h>

#define D_IN  128
#define D_OUT 32
#define H     512
#define W     512
#define W4    128               // W/4 float4 lanes per row
#define POS   (H * W4)          // 65536 float4 positions per slice

// v7: 3-kernel split. v1-v6 established: (a) total = sum(kernel dur) + ~140us
// fixed harness overhead (workspace re-poison fill) -- only kernel time is
// controllable; (b) conv cost ~= requested traffic / ~5.6 TB/s (per-CU
// outstanding-load cap; occupancy-insensitive); (c) cooperative launch adds
// ~20us -- use plain launches. The z-conv is pointwise in (h,w), so a
// dedicated z-pass reads each input byte ONCE (no d-overlap, no h-halo):
// requested 453 -> 176 MB for the heavy stage.

// ---------------- z-pass: stride-4 pad-3 conv along z ----------------
#define ZP_NTHR 512
#define ZP_K    2                          // float4 per thread
#define ZP_POSB (ZP_NTHR * ZP_K)           // 1024 positions per block
#define ZP_PT   (POS / ZP_POSB)            // 64 position tiles
#define ZP_DCH  8                          // d-chunks (4 outputs each)
#define ZP_GRID (ZP_PT * ZP_DCH)           // 512 blocks

__global__ __launch_bounds__(ZP_NTHR)
void zpass(const float* __restrict__ inp, float* __restrict__ zout,
           const float* __restrict__ bz_p) {
    const int pt   = blockIdx.x & (ZP_PT - 1);   // position tile
    const int c    = blockIdx.x / ZP_PT;         // d-chunk 0..7 (d = 4c..4c+3)
    const int pos0 = pt * ZP_POSB + threadIdx.x; // + ZP_NTHR for 2nd position

    const float bz = bz_p[0];
    const float iz = 1.0f / (2.0f * bz * bz);
    float wz[9];
#pragma unroll
    for (int k = 0; k < 9; ++k) {
        float dd = (float)(k - 4);
        wz[k] = expf(-dd * dd * iz);
    }

    const float4* in4 = (const float4*)inp;
    float4* zo4 = (float4*)zout;

    // acc[i][j]: output d=4c+i, position j -- all indices compile-time
    float4 acc[4][2];
#pragma unroll
    for (int i = 0; i < 4; ++i)
#pragma unroll
        for (int j = 0; j < 2; ++j)
            acc[i][j] = make_float4(0.f, 0.f, 0.f, 0.f);

    // chunk window: slices z0..z0+20; output i uses taps k = s - 4i in [0,8]
    const int z0 = 16 * c - 3;
#pragma unroll
    for (int s = 0; s < 21; ++s) {
        const int z = z0 + s;
        if ((unsigned)z < D_IN) {            // wave-uniform (z-padding)
            const float4* p = in4 + (size_t)z * POS + pos0;
            float4 v0 = p[0];
            float4 v1 = p[ZP_NTHR];
#pragma unroll
            for (int i = 0; i < 4; ++i) {
                const int k = s - 4 * i;     // compile-time per (s,i)
                if (k >= 0 && k <= 8) {
                    const float w = wz[k];
                    acc[i][0].x += v0.x * w; acc[i][0].y += v0.y * w;
                    acc[i][0].z += v0.z * w; acc[i][0].w += v0.w * w;
                    acc[i][1].x += v1.x * w; acc[i][1].y += v1.y * w;
                    acc[i][1].z += v1.z * w; acc[i][1].w += v1.w * w;
                }
            }
        }
    }

#pragma unroll
    for (int i = 0; i < 4; ++i) {
        const int d = 4 * c + i;
        zo4[(size_t)d * POS + pos0]           = acc[i][0];
        zo4[(size_t)d * POS + pos0 + ZP_NTHR] = acc[i][1];
    }
}

// ------------- hw-pass: fused h-conv + w-conv + block min/max -------------
#define HB    16           // output H rows per block
#define ZR    (HB + 8)     // rows incl. h-halo (24)
#define HW_NTHR 512
#define HW_GRID (D_OUT * (H / HB))   // 32 * 32 = 1024 blocks

__global__ __launch_bounds__(HW_NTHR)
void hwpass(const float* __restrict__ zin, float* __restrict__ out,
            const float* __restrict__ bxy_p,
            float* __restrict__ blkMin, float* __restrict__ blkMax) {
    __shared__ float zbuf[ZR * W];   // 48 KiB -> 3 blocks/CU
    __shared__ float smin[8], smax[8];

    const int tid = threadIdx.x;
    const int d  = blockIdx.x >> 5;
    const int h0 = (blockIdx.x & 31) * HB;

    const float bx = bxy_p[0];
    const float ix = 1.0f / (2.0f * bx * bx);
    float wx[9];
#pragma unroll
    for (int k = 0; k < 9; ++k) {
        float dd = (float)(k - 4);
        wx[k] = expf(-dd * dd * ix);
    }

    const float4* zin4 = (const float4*)zin;
    float4* z4 = (float4*)zbuf;

    // stage rows [h0-4, h0+20) of slice d (h-padding -> zero)
    for (int t = tid; t < ZR * W4; t += HW_NTHR) {   // 6 iterations
        int r  = t >> 7;
        int c4 = t & (W4 - 1);
        int h  = h0 - 4 + r;
        z4[t] = ((unsigned)h < H) ? zin4[(size_t)d * POS + h * W4 + c4]
                                  : make_float4(0.f, 0.f, 0.f, 0.f);
    }
    __syncthreads();

    const int lane = tid & 63;
    float lmin =  3.402823466e38f;
    float lmax = -3.402823466e38f;
    float4* out4 = (float4*)out;

    for (int t = tid; t < HB * W4; t += HW_NTHR) {   // 4 iterations
        int r  = t >> 7;            // wave-uniform
        int c4 = t & (W4 - 1);      // consecutive across lanes

        // h-conv at (r, c4)
        float4 v = make_float4(0.f, 0.f, 0.f, 0.f);
#pragma unroll
        for (int k = 0; k < 9; ++k) {
            float4 z = z4[(r + k) * W4 + c4];
            v.x += z.x * wx[k]; v.y += z.y * wx[k];
            v.z += z.z * wx[k]; v.w += z.w * wx[k];
        }

        // w-neighbors from adjacent lanes
        float4 va, vc;
        va.x = __shfl_up(v.x, 1, 64);   va.y = __shfl_up(v.y, 1, 64);
        va.z = __shfl_up(v.z, 1, 64);   va.w = __shfl_up(v.w, 1, 64);
        vc.x = __shfl_down(v.x, 1, 64); vc.y = __shfl_down(v.y, 1, 64);
        vc.z = __shfl_down(v.z, 1, 64); vc.w = __shfl_down(v.w, 1, 64);

        // wave-edge lanes recompute neighbor column (OOB -> zero = w pad)
        if (lane == 0 || lane == 63) {
            int c4n = c4 + ((lane == 0) ? -1 : 1);
            float4 vn = make_float4(0.f, 0.f, 0.f, 0.f);
            if ((unsigned)c4n < W4) {
#pragma unroll
                for (int k = 0; k < 9; ++k) {
                    float4 z = z4[(r + k) * W4 + c4n];
                    vn.x += z.x * wx[k]; vn.y += z.y * wx[k];
                    vn.z += z.z * wx[k]; vn.w += z.w * wx[k];
                }
            }
            if (lane == 0) va = vn; else vc = vn;
        }

        float win[12] = {va.x, va.y, va.z, va.w,
                         v.x,  v.y,  v.z,  v.w,
                         vc.x, vc.y, vc.z, vc.w};
        float4 o = make_float4(0.f, 0.f, 0.f, 0.f);
#pragma unroll
        for (int k = 0; k < 9; ++k) {
            o.x += win[k]     * wx[k];
            o.y += win[k + 1] * wx[k];
            o.z += win[k + 2] * wx[k];
            o.w += win[k + 3] * wx[k];
        }
        out4[((size_t)d * H + h0 + r) * W4 + c4] = o;
        lmin = fminf(lmin, fminf(fminf(o.x, o.y), fminf(o.z, o.w)));
        lmax = fmaxf(lmax, fmaxf(fmaxf(o.x, o.y), fmaxf(o.z, o.w)));
    }

    // block min/max reduction (8 waves)
#pragma unroll
    for (int off = 32; off > 0; off >>= 1) {
        lmin = fminf(lmin, __shfl_down(lmin, off, 64));
        lmax = fmaxf(lmax, __shfl_down(lmax, off, 64));
    }
    int wv = tid >> 6;
    if (lane == 0) { smin[wv] = lmin; smax[wv] = lmax; }
    __syncthreads();
    if (tid == 0) {
        float mn = smin[0], mx = smax[0];
#pragma unroll
        for (int i = 1; i < 8; ++i) { mn = fminf(mn, smin[i]); mx = fmaxf(mx, smax[i]); }
        blkMin[blockIdx.x] = mn;
        blkMax[blockIdx.x] = mx;
    }
}

// ---------------- norm: per-block reduce of min/max + scale ----------------
#define NORM_NTHR  256
#define NORM_F4_PER_THR 4
#define NORM_GRID  ((D_OUT * H * W4) / (NORM_NTHR * NORM_F4_PER_THR))  // 2048

__global__ __launch_bounds__(NORM_NTHR)
void norm_kernel(const float* __restrict__ in, float* __restrict__ out,
                 const float* __restrict__ blkMin, const float* __restrict__ blkMax) {
    float lmin =  3.402823466e38f;
    float lmax = -3.402823466e38f;
    for (int i = threadIdx.x; i < HW_GRID; i += NORM_NTHR) {   // 4 iterations
        lmin = fminf(lmin, blkMin[i]);
        lmax = fmaxf(lmax, blkMax[i]);
    }
#pragma unroll
    for (int off = 32; off > 0; off >>= 1) {
        lmin = fminf(lmin, __shfl_down(lmin, off, 64));
        lmax = fmaxf(lmax, __shfl_down(lmax, off, 64));
    }
    __shared__ float smin[4], smax[4];
    int lane = threadIdx.x & 63, wv = threadIdx.x >> 6;
    if (lane == 0) { smin[wv] = lmin; smax[wv] = lmax; }
    __syncthreads();
    float mn  = fminf(fminf(smin[0], smin[1]), fminf(smin[2], smin[3]));
    float mx  = fmaxf(fmaxf(smax[0], smax[1]), fmaxf(smax[2], smax[3]));
    float inv = 1.0f / (mx - mn);

    const float4* in4  = (const float4*)in;
    float4*       out4 = (float4*)out;
    int base = blockIdx.x * (NORM_NTHR * NORM_F4_PER_THR) + threadIdx.x;
#pragma unroll
    for (int j = 0; j < NORM_F4_PER_THR; ++j) {
        int idx = base + j * NORM_NTHR;
        float4 v = in4[idx];
        out4[idx] = make_float4((v.x - mn) * inv, (v.y - mn) * inv,
                                (v.z - mn) * inv, (v.w - mn) * inv);
    }
}

extern "C" void kernel_launch(void* const* d_in, const int* in_sizes, int n_in,
                              void* d_out, int out_size, void* d_ws, size_t ws_size,
                              hipStream_t stream) {
    const float* inp    = (const float*)d_in[0];
    // mu_z / sig_z only produce a positive global scale, which cancels in the
    // min-max normalization -> unused.
    const float* bet_xy = (const float*)d_in[3];
    const float* bet_z  = (const float*)d_in[4];
    float* out = (float*)d_out;

    char* ws = (char*)d_ws;
    float* blkMin = (float*)(ws + 4096);                 // 1024 floats
    float* blkMax = (float*)(ws + 8192);                 // 1024 floats
    float* zbufG  = (float*)(ws + 65536);                // 32 MiB z-conv output
    float* bufB   = (float*)(ws + 65536 + 33554432);     // 32 MiB hw output

    zpass<<<ZP_GRID, ZP_NTHR, 0, stream>>>(inp, zbufG, bet_z);
    hwpass<<<HW_GRID, HW_NTHR, 0, stream>>>(zbufG, bufB, bet_xy, blkMin, blkMax);
    norm_kernel<<<NORM_GRID, NORM_NTHR, 0, stream>>>(bufB, out, blkMin, blkMax);
}

// Round 7
// 240.074 us; speedup vs baseline: 1.1906x; 1.0350x over previous
//
#include <hip/hip_runtime.h>

#define D_IN  128
#define D_OUT 32
#define H     512
#define W     512
#define W4    128               // W/4 float4 lanes per row
#define POS   (H * W4)          // float4 per input slice
#define HB    16                // output H rows per block
#define ZR    (HB + 8)          // rows incl. h-halo (24)
#define NTHR  512
#define NPOS  6                 // ZR*W4 / NTHR positions per thread
#define CONV_GRID ((D_OUT / 2) * (H / HB))   // 16 * 32 = 512 blocks

// v8 = v4 + d-pair register carry. Each block computes outputs d and d+1 from
// the UNION of their z-windows (13 slices instead of 18): z-conv for d goes to
// zbuf, z-conv for d+1 is held in 6 registers (static idx) and flushed through
// the same zbuf after d's h+w conv. Requested traffic 453 -> ~319 MB with NO
// extra global round-trip (v7's mistake). Two 7/6-deep register load batches
// per position (v4-proven depth); live set ~93 VGPR < 128 cap (v5's spill
// lesson: stay under the default cap, don't force occupancy bounds).
__global__ __launch_bounds__(NTHR)
void conv3d_fused(const float* __restrict__ inp, float* __restrict__ out,
                  const float* __restrict__ bxy_p, const float* __restrict__ bz_p,
                  float* __restrict__ blkMin, float* __restrict__ blkMax) {
    __shared__ float zbuf[ZR * W];   // 48 KiB
    __shared__ float smin[8], smax[8];

    const int tid = threadIdx.x;
    const int dp = blockIdx.x >> 5;        // 0..15 (d-pair)
    const int d  = 2 * dp;
    const int h0 = (blockIdx.x & 31) * HB;

    const float bz = bz_p[0], bx = bxy_p[0];
    const float iz = 1.0f / (2.0f * bz * bz);
    const float ix = 1.0f / (2.0f * bx * bx);
    float wz[9], wx[9];
#pragma unroll
    for (int k = 0; k < 9; ++k) {
        float dd = (float)(k - 4);
        wz[k] = expf(-dd * dd * iz);
        wx[k] = expf(-dd * dd * ix);
    }

    const float4* in4 = (const float4*)inp;
    float4* z4 = (float4*)zbuf;
    const float4 f4z = make_float4(0.f, 0.f, 0.f, 0.f);

    // per-thread tile positions: pos_j = j*512 + tid; r = pos>>7 wave-uniform
    int  rowOff[NPOS];
    bool rowOk[NPOS];
#pragma unroll
    for (int j = 0; j < NPOS; ++j) {
        int pos = j * NTHR + tid;
        int r   = pos >> 7;
        int c4  = pos & (W4 - 1);
        int h   = h0 - 4 + r;
        rowOk[j]  = (unsigned)h < H;
        rowOff[j] = h * W4 + c4;
    }

#define FMA4(A, V, Wc) do { (A).x += (V).x * (Wc); (A).y += (V).y * (Wc); \
                            (A).z += (V).z * (Wc); (A).w += (V).w * (Wc); } while (0)

    // union window for outputs d, d+1: z = z0 .. z0+12
    const int z0 = 4 * d - 3;
    const bool interior = (dp >= 1) && (dp <= 14);   // all 13 slices in range

    float4 accN[NPOS];   // z-conv for d+1, held across d's flush

    // ---- Phase A: z-conv for both outputs; d -> zbuf, d+1 -> registers ----
#pragma unroll
    for (int j = 0; j < NPOS; ++j) {
        float4 a0 = f4z, a1 = f4z;
        if (rowOk[j]) {
            if (interior) {
                const float4* p = in4 + (size_t)z0 * POS + rowOff[j];
                float4 vv[7];
#pragma unroll
                for (int s = 0; s < 7; ++s) vv[s] = p[s * POS];
                __builtin_amdgcn_sched_barrier(0);   // 7 loads in flight
#pragma unroll
                for (int s = 0; s < 7; ++s) FMA4(a0, vv[s], wz[s]);
#pragma unroll
                for (int s = 4; s < 7; ++s) FMA4(a1, vv[s], wz[s - 4]);
                float4 uu[6];
#pragma unroll
                for (int s = 0; s < 6; ++s) uu[s] = p[(s + 7) * POS];
                __builtin_amdgcn_sched_barrier(0);   // 6 loads in flight
#pragma unroll
                for (int s = 7; s < 9; ++s)  FMA4(a0, uu[s - 7], wz[s]);
#pragma unroll
                for (int s = 7; s < 13; ++s) FMA4(a1, uu[s - 7], wz[s - 4]);
            } else {
#pragma unroll
                for (int s = 0; s < 13; ++s) {
                    int z = z0 + s;                   // wave-uniform predicate
                    if ((unsigned)z < D_IN) {
                        float4 v = in4[(size_t)z * POS + rowOff[j]];
                        if (s <= 8) FMA4(a0, v, wz[s]);
                        if (s >= 4) FMA4(a1, v, wz[s - 4]);
                    }
                }
            }
        }
        z4[j * NTHR + tid] = a0;
        accN[j] = a1;
    }

    // ---- fused h+w conv from zbuf (v4-proven), for output dOut ----
    const int lane = tid & 63;
    float lmin =  3.402823466e38f;
    float lmax = -3.402823466e38f;
    float4* out4 = (float4*)out;

    auto hwconv = [&](int dOut) {
        for (int t = tid; t < HB * W4; t += NTHR) {   // 4 iterations
            int r  = t >> 7;            // wave-uniform
            int c4 = t & (W4 - 1);      // consecutive across lanes

            // h-conv at (r, c4)
            float4 v = f4z;
#pragma unroll
            for (int k = 0; k < 9; ++k) {
                float4 z = z4[(r + k) * W4 + c4];
                FMA4(v, z, wx[k]);
            }

            // w-neighbors from adjacent lanes
            float4 va, vc;
            va.x = __shfl_up(v.x, 1, 64);   va.y = __shfl_up(v.y, 1, 64);
            va.z = __shfl_up(v.z, 1, 64);   va.w = __shfl_up(v.w, 1, 64);
            vc.x = __shfl_down(v.x, 1, 64); vc.y = __shfl_down(v.y, 1, 64);
            vc.z = __shfl_down(v.z, 1, 64); vc.w = __shfl_down(v.w, 1, 64);

            // wave-edge lanes recompute neighbor column (OOB -> zero = w pad)
            if (lane == 0 || lane == 63) {
                int c4n = c4 + ((lane == 0) ? -1 : 1);
                float4 vn = f4z;
                if ((unsigned)c4n < W4) {
#pragma unroll
                    for (int k = 0; k < 9; ++k) {
                        float4 z = z4[(r + k) * W4 + c4n];
                        FMA4(vn, z, wx[k]);
                    }
                }
                if (lane == 0) va = vn; else vc = vn;
            }

            float win[12] = {va.x, va.y, va.z, va.w,
                             v.x,  v.y,  v.z,  v.w,
                             vc.x, vc.y, vc.z, vc.w};
            float4 o = f4z;
#pragma unroll
            for (int k = 0; k < 9; ++k) {
                o.x += win[k]     * wx[k];
                o.y += win[k + 1] * wx[k];
                o.z += win[k + 2] * wx[k];
                o.w += win[k + 3] * wx[k];
            }
            out4[((size_t)dOut * H + h0 + r) * W4 + c4] = o;
            lmin = fminf(lmin, fminf(fminf(o.x, o.y), fminf(o.z, o.w)));
            lmax = fmaxf(lmax, fmaxf(fmaxf(o.x, o.y), fmaxf(o.z, o.w)));
        }
    };

    __syncthreads();          // zbuf (output d) complete
    hwconv(d);
    __syncthreads();          // all reads of zbuf done
#pragma unroll
    for (int j = 0; j < NPOS; ++j) z4[j * NTHR + tid] = accN[j];
    __syncthreads();          // zbuf (output d+1) complete
    hwconv(d + 1);

    // ---- block min/max reduction (8 waves) ----
#pragma unroll
    for (int off = 32; off > 0; off >>= 1) {
        lmin = fminf(lmin, __shfl_down(lmin, off, 64));
        lmax = fmaxf(lmax, __shfl_down(lmax, off, 64));
    }
    int wv = tid >> 6;  // 0..7
    if (lane == 0) { smin[wv] = lmin; smax[wv] = lmax; }
    __syncthreads();
    if (tid == 0) {
        float mn = smin[0], mx = smax[0];
#pragma unroll
        for (int i = 1; i < 8; ++i) { mn = fminf(mn, smin[i]); mx = fmaxf(mx, smax[i]); }
        blkMin[blockIdx.x] = mn;
        blkMax[blockIdx.x] = mx;
    }
#undef FMA4
}

// Normalize; each block reduces the per-block min/max arrays itself
// (L2-hot, fully parallel) -> no serialized single-block reduce kernel.
#define NORM_NTHR  256
#define NORM_F4_PER_THR 4
#define NORM_GRID  ((D_OUT * H * W4) / (NORM_NTHR * NORM_F4_PER_THR))  // 2048

__global__ __launch_bounds__(NORM_NTHR)
void norm_kernel(const float* __restrict__ in, float* __restrict__ out,
                 const float* __restrict__ blkMin, const float* __restrict__ blkMax) {
    float lmin =  3.402823466e38f;
    float lmax = -3.402823466e38f;
    for (int i = threadIdx.x; i < CONV_GRID; i += NORM_NTHR) {   // 2 iterations
        lmin = fminf(lmin, blkMin[i]);
        lmax = fmaxf(lmax, blkMax[i]);
    }
#pragma unroll
    for (int off = 32; off > 0; off >>= 1) {
        lmin = fminf(lmin, __shfl_down(lmin, off, 64));
        lmax = fmaxf(lmax, __shfl_down(lmax, off, 64));
    }
    __shared__ float smin[4], smax[4];
    int lane = threadIdx.x & 63, wv = threadIdx.x >> 6;
    if (lane == 0) { smin[wv] = lmin; smax[wv] = lmax; }
    __syncthreads();
    float mn  = fminf(fminf(smin[0], smin[1]), fminf(smin[2], smin[3]));
    float mx  = fmaxf(fmaxf(smax[0], smax[1]), fmaxf(smax[2], smax[3]));
    float inv = 1.0f / (mx - mn);

    const float4* in4  = (const float4*)in;
    float4*       out4 = (float4*)out;
    int base = blockIdx.x * (NORM_NTHR * NORM_F4_PER_THR) + threadIdx.x;
#pragma unroll
    for (int j = 0; j < NORM_F4_PER_THR; ++j) {
        int idx = base + j * NORM_NTHR;
        float4 v = in4[idx];
        out4[idx] = make_float4((v.x - mn) * inv, (v.y - mn) * inv,
                                (v.z - mn) * inv, (v.w - mn) * inv);
    }
}

extern "C" void kernel_launch(void* const* d_in, const int* in_sizes, int n_in,
                              void* d_out, int out_size, void* d_ws, size_t ws_size,
                              hipStream_t stream) {
    const float* inp    = (const float*)d_in[0];
    // mu_z / sig_z only produce a positive global scale, which cancels in the
    // min-max normalization -> unused.
    const float* bet_xy = (const float*)d_in[3];
    const float* bet_z  = (const float*)d_in[4];
    float* out = (float*)d_out;

    char* ws = (char*)d_ws;
    float* blkMin = (float*)(ws + 4096);         // 512 floats
    float* blkMax = (float*)(ws + 8192);         // 512 floats
    float* bufA   = (float*)(ws + 65536);        // 32 MiB conv output

    conv3d_fused<<<CONV_GRID, NTHR, 0, stream>>>(inp, bufA, bet_xy, bet_z, blkMin, blkMax);
    norm_kernel<<<NORM_GRID, NORM_NTHR, 0, stream>>>(bufA, out, blkMin, blkMax);
}